// Round 1
// baseline (136.446 us; speedup 1.0000x reference)
//
#include <hip/hip_runtime.h>

// Problem constants (from reference)
#define N_BUSES     2000
#define BATCH       32
#define EDGES_PER_B 6000
#define TOTAL_BUSES (BATCH * N_BUSES)   // 64000
#define TOTAL_EDGES (BATCH * EDGES_PER_B) // 192000

// Hash table for last-write-wins dedup of duplicate (b,i,j) edges
#define HBITS 19
#define HSIZE (1 << HBITS)   // 524288 slots, load factor ~0.37
#define HMASK (HSIZE - 1)

// Workspace layout (bytes). ws is 256-aligned (hipMalloc).
#define OFF_ACC    0                              // 8 doubles: d1re,d1im,d2,d3,mse
#define OFF_BSTATS 64                             // 3*BATCH floats: Smean_re, Smean_im, Vm_mean
#define OFF_YV     512                            // 2*TOTAL_BUSES floats (YV re/im)
#define OFF_HKEY   (OFF_YV + 2 * TOTAL_BUSES * 4) // HSIZE ints
#define OFF_HVAL   (OFF_HKEY + HSIZE * 4)         // HSIZE ints
// total ~4.7 MB

__device__ __forceinline__ unsigned hash_key(int key) {
    return ((unsigned)key * 2654435761u) >> (32 - HBITS);
}

__global__ void init_ws(float* __restrict__ yv, int* __restrict__ hkey,
                        int* __restrict__ hval, double* __restrict__ acc) {
    int i = blockIdx.x * blockDim.x + threadIdx.x;   // grid covers HSIZE exactly
    hkey[i] = -1;
    hval[i] = -1;
    if (i < 2 * TOTAL_BUSES) yv[i] = 0.0f;
    if (i < 8) acc[i] = 0.0;
}

// Per-batch means of S (complex) and Vm — only consumed when an exact 0 occurs,
// but computed faithfully to the reference.
__global__ void batch_stats(const float* __restrict__ x, float* __restrict__ bstats) {
    int b = blockIdx.x;
    int tid = threadIdx.x;
    double sre = 0.0, sim = 0.0, vm = 0.0;
    for (int i = tid; i < N_BUSES; i += blockDim.x) {
        const float* row = x + (size_t)(b * N_BUSES + i) * 6;
        sre += (double)row[0];
        sim += (double)row[1];
        vm  += (double)row[2];
    }
    for (int off = 32; off > 0; off >>= 1) {
        sre += __shfl_down(sre, off, 64);
        sim += __shfl_down(sim, off, 64);
        vm  += __shfl_down(vm,  off, 64);
    }
    __shared__ double sh[3][4];
    int wave = tid >> 6, lane = tid & 63;
    if (lane == 0) { sh[0][wave] = sre; sh[1][wave] = sim; sh[2][wave] = vm; }
    __syncthreads();
    if (tid == 0) {
        double a = 0, c = 0, d = 0;
        for (int w = 0; w < 4; w++) { a += sh[0][w]; c += sh[1][w]; d += sh[2][w]; }
        bstats[b]             = (float)(a / N_BUSES);
        bstats[BATCH + b]     = (float)(c / N_BUSES);
        bstats[2 * BATCH + b] = (float)(d / N_BUSES);
    }
}

// Pass A: record, per (b,i,j) key, the maximum edge id (numpy fancy-assign:
// last write wins; "last" = highest flat edge index).
__global__ void edge_insert(const int* __restrict__ ei,
                            int* __restrict__ hkey, int* __restrict__ hval) {
    int m = blockIdx.x * blockDim.x + threadIdx.x;   // grid covers TOTAL_EDGES exactly
    int b = m / EDGES_PER_B;
    int i = ei[m] % N_BUSES;
    int j = ei[TOTAL_EDGES + m] % N_BUSES;
    int key = (b * N_BUSES + i) * N_BUSES + j;       // < 128e6, fits int32
    unsigned h = hash_key(key);
    while (true) {
        int prev = atomicCAS(&hkey[h], -1, key);
        if (prev == -1 || prev == key) break;
        h = (h + 1) & HMASK;
    }
    atomicMax(&hval[h], m);
}

// Pass B: only the winning edge per key contributes YV[b,i] += adm * V[b,j].
__global__ void edge_accum(const int* __restrict__ ei, const float* __restrict__ ea,
                           const float* __restrict__ outputs,
                           const int* __restrict__ hkey, const int* __restrict__ hval,
                           float* __restrict__ yv) {
    int m = blockIdx.x * blockDim.x + threadIdx.x;
    int b = m / EDGES_PER_B;
    int i = ei[m] % N_BUSES;
    int j = ei[TOTAL_EDGES + m] % N_BUSES;
    int key = (b * N_BUSES + i) * N_BUSES + j;
    unsigned h = hash_key(key);
    while (hkey[h] != key) h = (h + 1) & HMASK;
    if (hval[h] != m) return;                        // a later duplicate overwrote this edge
    float ar = ea[2 * m], ai = ea[2 * m + 1];
    int vj = (b * N_BUSES + j) * 2;
    float vr = outputs[vj], vi = outputs[vj + 1];
    int ti = (b * N_BUSES + i) * 2;
    atomicAdd(&yv[ti],     ar * vr - ai * vi);
    atomicAdd(&yv[ti + 1], ar * vi + ai * vr);
}

__device__ __forceinline__ void block_reduce_5(double v0, double v1, double v2,
                                               double v3, double v4, double* acc) {
    for (int off = 32; off > 0; off >>= 1) {
        v0 += __shfl_down(v0, off, 64);
        v1 += __shfl_down(v1, off, 64);
        v2 += __shfl_down(v2, off, 64);
        v3 += __shfl_down(v3, off, 64);
        v4 += __shfl_down(v4, off, 64);
    }
    __shared__ double sh[5][4];
    int tid = threadIdx.x;
    int wave = tid >> 6, lane = tid & 63;
    if (lane == 0) {
        sh[0][wave] = v0; sh[1][wave] = v1; sh[2][wave] = v2;
        sh[3][wave] = v3; sh[4][wave] = v4;
    }
    __syncthreads();
    if (tid == 0) {
        double a0 = 0, a1 = 0, a2 = 0, a3 = 0, a4 = 0;
        for (int w = 0; w < 4; w++) {
            a0 += sh[0][w]; a1 += sh[1][w]; a2 += sh[2][w];
            a3 += sh[3][w]; a4 += sh[4][w];
        }
        atomicAdd(&acc[0], a0); atomicAdd(&acc[1], a1); atomicAdd(&acc[2], a2);
        atomicAdd(&acc[3], a3); atomicAdd(&acc[4], a4);
    }
}

__global__ void loss_kernel(const float* __restrict__ x, const float* __restrict__ outputs,
                            const float* __restrict__ labels, const float* __restrict__ yv,
                            const float* __restrict__ bstats, double* __restrict__ acc) {
    int idx = blockIdx.x * blockDim.x + threadIdx.x;  // grid covers TOTAL_BUSES exactly
    int b = idx / N_BUSES;
    const float* row = x + (size_t)idx * 6;
    float sre = row[0], sim = row[1], Vm = row[2];
    float bt0 = row[3], bt1 = row[4], bt2 = row[5];
    float vr = outputs[idx * 2], vi = outputs[idx * 2 + 1];
    float yvr = yv[idx * 2], yvi = yv[idx * 2 + 1];
    // Spred = V * conj(YV)
    float spr = vr * yvr + vi * yvi;
    float spi = vi * yvr - vr * yvi;
    // S_inverse = where(S != 0, 1/S, 1/S_mean); norm = |S_inverse|
    float ir, ii;
    if (sre != 0.0f || sim != 0.0f) {
        float den = sre * sre + sim * sim;
        ir = sre / den; ii = -sim / den;
    } else {
        float mr = bstats[b], mi = bstats[BATCH + b];
        float den = mr * mr + mi * mi;
        ir = mr / den; ii = -mi / den;
    }
    float sinv_norm = sqrtf(ir * ir + ii * ii);
    // result1 = (Spred - S)^2 * bt0 (complex); result2 = (Re diff)^2 * bt1 (real)
    float cr = spr - sre, ci = spi - sim;
    float t_d1re = sinv_norm * ((cr * cr - ci * ci) * bt0 + (cr * cr) * bt1);
    float t_d1im = sinv_norm * (2.0f * cr * ci * bt0);
    float vminv = (Vm != 0.0f) ? (1.0f / Vm) : (1.0f / bstats[2 * BATCH + b]);
    float vmag = sqrtf(vr * vr + vi * vi);
    float t_d2 = fabsf(vmag * (bt1 + bt2) - Vm) * vminv;
    float t_d3 = fabsf(vi * bt2) * vminv;
    float e0 = vr - labels[idx * 2], e1 = vi - labels[idx * 2 + 1];
    float t_mse = e0 * e0 + e1 * e1;
    block_reduce_5((double)t_d1re, (double)t_d1im, (double)t_d2, (double)t_d3,
                   (double)t_mse, acc);
}

__global__ void finalize(const double* __restrict__ acc, float* __restrict__ out,
                         int out_size) {
    if (threadIdx.x != 0 || blockIdx.x != 0) return;
    double inv = 1.0 / (double)TOTAL_BUSES;
    double d1re = acc[0] * inv, d1im = acc[1] * inv;
    double d2 = acc[2] * inv, d3 = acc[3] * inv;
    double mse = acc[4] / (2.0 * (double)TOTAL_BUSES);
    double phre = d1re + d2 + d3, phim = d1im;
    double lre = mse + 0.1 * phre, lim = 0.1 * phim;
    if (out_size == 8) {
        // complex64 viewed as float32 pairs: loss, physics, d1 complex; d2, d3 real
        out[0] = (float)lre;  out[1] = (float)lim;
        out[2] = (float)phre; out[3] = (float)phim;
        out[4] = (float)d1re; out[5] = (float)d1im;
        out[6] = (float)d2;   out[7] = (float)d3;
    } else {
        // real parts in return order (optimal act regardless of ref convention)
        float vals[5] = {(float)lre, (float)phre, (float)d1re, (float)d2, (float)d3};
        int n = out_size < 5 ? out_size : 5;
        for (int k = 0; k < n; k++) out[k] = vals[k];
        for (int k = 5; k < out_size && k < 64; k++) out[k] = 0.0f;
    }
}

extern "C" void kernel_launch(void* const* d_in, const int* in_sizes, int n_in,
                              void* d_out, int out_size, void* d_ws, size_t ws_size,
                              hipStream_t stream) {
    const float* x       = (const float*)d_in[0];
    const float* ea      = (const float*)d_in[1];
    const int*   ei      = (const int*)d_in[2];
    const float* outputs = (const float*)d_in[3];
    const float* labels  = (const float*)d_in[4];

    char* ws = (char*)d_ws;
    double* acc   = (double*)(ws + OFF_ACC);
    float* bstats = (float*)(ws + OFF_BSTATS);
    float* yv     = (float*)(ws + OFF_YV);
    int* hkey     = (int*)(ws + OFF_HKEY);
    int* hval     = (int*)(ws + OFF_HVAL);

    init_ws<<<HSIZE / 256, 256, 0, stream>>>(yv, hkey, hval, acc);
    batch_stats<<<BATCH, 256, 0, stream>>>(x, bstats);
    edge_insert<<<TOTAL_EDGES / 256, 256, 0, stream>>>(ei, hkey, hval);
    edge_accum<<<TOTAL_EDGES / 256, 256, 0, stream>>>(ei, ea, outputs, hkey, hval, yv);
    loss_kernel<<<TOTAL_BUSES / 256, 256, 0, stream>>>(x, outputs, labels, yv, bstats, acc);
    finalize<<<1, 64, 0, stream>>>(acc, (float*)d_out, out_size);
}